// Round 12
// baseline (1069.340 us; speedup 1.0000x reference)
//
#include <hip/hip_runtime.h>

#define TT 1024
#define NB 32
#define NJ 128
#define NI 512
#define KD 16
#define LVL 1048576                 // shorts per level in WF (512*2048)
#define XLVL 4194304                // shorts per level in XF (1024*32*128)

typedef short bf16x8 __attribute__((ext_vector_type(8)));
typedef float floatx4 __attribute__((ext_vector_type(4)));

struct S3 { short h, m, l; };

// 3-way bf16 truncation split: v = h + m + l + O(2^-27 v). Residuals exact.
__device__ __forceinline__ S3 split3(float v) {
    S3 o;
    unsigned hb = __float_as_uint(v) & 0xFFFF0000u;
    float hf = __uint_as_float(hb);
    float r1 = v - hf;
    unsigned mb = __float_as_uint(r1) & 0xFFFF0000u;
    float mf = __uint_as_float(mb);
    float r2 = r1 - mf;
    unsigned lb = __float_as_uint(r2) & 0xFFFF0000u;
    o.h = (short)(hb >> 16);
    o.m = (short)(mb >> 16);
    o.l = (short)(lb >> 16);
    return o;
}

// ---------------- DCLS: W in 3-level bf16 MFMA B-frag layout [R10-proven] ----------------
__global__ __launch_bounds__(256) void dcls_kern(const float* __restrict__ w,
                                                 const float* __restrict__ P,
                                                 short* __restrict__ WF) {
    int idx = blockIdx.x * 256 + threadIdx.x;   // idx = i*128 + j
    int j = idx & (NJ - 1);
    int i = idx >> 7;
    float wv = w[i * NJ + j];
    float c  = P[i * NJ + j] + (float)(KD / 2);
    float g[KD];
    float s = 0.f;
#pragma unroll
    for (int k = 0; k < KD; ++k) {
        float u = (float)k - c;
        g[k] = expf(-2.0f * u * u);
        s += g[k];
    }
    float inv = wv / (s + 1e-7f);
    size_t base = (size_t)(i >> 4) * 32768 + (size_t)(j >> 3) * 128 + (i & 15) * 8 + (j & 7);
#pragma unroll
    for (int d = 0; d < KD; ++d) {
        S3 sp = split3(g[(KD - 1) - d] * inv);   // conv flip
        size_t off = base + (size_t)d * 2048;
        WF[off]           = sp.h;
        WF[off + LVL]     = sp.m;
        WF[off + 2 * LVL] = sp.l;
    }
}

// ---------------- x pre-split: x fp32 -> XF[3][t][b][j] bf16 (split once, not 16x) ----
__global__ __launch_bounds__(256) void xsplit_kern(const float* __restrict__ x,
                                                   short* __restrict__ XF) {
    size_t e0 = ((size_t)blockIdx.x * 256 + threadIdx.x) * 8;   // 8 elems/thread
    float4 v0 = *(const float4*)(x + e0);
    float4 v1 = *(const float4*)(x + e0 + 4);
    S3 a0 = split3(v0.x), a1 = split3(v0.y), a2 = split3(v0.z), a3 = split3(v0.w);
    S3 a4 = split3(v1.x), a5 = split3(v1.y), a6 = split3(v1.z), a7 = split3(v1.w);
    bf16x8 h8, m8, l8;
    h8[0]=a0.h; h8[1]=a1.h; h8[2]=a2.h; h8[3]=a3.h; h8[4]=a4.h; h8[5]=a5.h; h8[6]=a6.h; h8[7]=a7.h;
    m8[0]=a0.m; m8[1]=a1.m; m8[2]=a2.m; m8[3]=a3.m; m8[4]=a4.m; m8[5]=a5.m; m8[6]=a6.m; m8[7]=a7.m;
    l8[0]=a0.l; l8[1]=a1.l; l8[2]=a2.l; l8[3]=a3.l; l8[4]=a4.l; l8[5]=a5.l; l8[6]=a6.l; l8[7]=a7.l;
    *(bf16x8*)(XF + e0)            = h8;
    *(bf16x8*)(XF + XLVL + e0)     = m8;
    *(bf16x8*)(XF + 2 * XLVL + e0) = l8;
}

// ---------------- MFMA conv (XF path): staging = pure data movement ----------------
// R10 structure exactly; the only change: A staging loads pre-split bf16 from XF
// (6x bf16x8 global) instead of fp32 + split3. 6 MFMA products unchanged.
__global__ __launch_bounds__(256, 3) void conv_mfma_xf(const short* __restrict__ XF,
                                                       const short* __restrict__ WF,
                                                       float* __restrict__ y) {
    __shared__ __align__(16) short PA[128][64];   // [Ah | Am], 8x16B chunks/row
    __shared__ __align__(16) short PL[128][64];   // [Al | --]

    const int t0 = blockIdx.x * 128;
    const int i0 = blockIdx.y * 128;
    const int b  = blockIdx.z;
    const int tid = threadIdx.x;

    const int ch   = tid & 3;            // staging: 4 chunks x 8 bf16 = 32 cols
    const int rw2  = tid >> 2;           // 0..63
    const int l    = tid & 63;
    const int wid  = tid >> 6;           // wave 0..3
    const int lr16 = l & 15;
    const int kb   = l >> 4;             // k-octet 0..3
    const int wm   = wid >> 1;           // 0..1 -> 64 t-rows
    const int wn   = wid & 1;            // 0..1 -> 64 i-cols

    const short* pnf[4];
#pragma unroll
    for (int nf = 0; nf < 4; ++nf) {
        int ig = (i0 + wn * 64 + nf * 16) >> 4;
        pnf[nf] = WF + (size_t)ig * 32768 + l * 8;
    }

    floatx4 acc[4][4];
#pragma unroll
    for (int mf = 0; mf < 4; ++mf)
#pragma unroll
        for (int nf = 0; nf < 4; ++nf)
#pragma unroll
            for (int e = 0; e < 4; ++e) acc[mf][nf][e] = 0.f;

    bf16x8 xh[2], xm[2], xl[2];
    bf16x8 W0h[4], W0m[4], W0l[4], W1h[4], W1m[4], W1l[4];

#define LOADW(K, H, M, L_) {                                                    \
    int koff = ((((K) >> 2) * 16 + ((K) & 3) * 4)) * 128;                       \
    _Pragma("unroll") for (int nf = 0; nf < 4; ++nf) {                          \
        const short* p = pnf[nf] + koff;                                        \
        H[nf]  = *(const bf16x8*)(p);                                           \
        M[nf]  = *(const bf16x8*)(p + LVL);                                     \
        L_[nf] = *(const bf16x8*)(p + 2 * LVL); } }

#define LOADX(K) {                                                              \
    int dn = (K) >> 2, j0n = ((K) & 3) << 5;                                    \
    _Pragma("unroll") for (int s = 0; s < 2; ++s) {                             \
        int r = rw2 + s * 64;                                                   \
        int t = t0 + r - dn;                                                    \
        bf16x8 z8 = (bf16x8)(short)0;                                           \
        xh[s] = z8; xm[s] = z8; xl[s] = z8;                                     \
        if (t >= 0) {                                                           \
            const short* xp = XF + ((size_t)t * NB + b) * NJ + j0n + ch * 8;    \
            xh[s] = *(const bf16x8*)(xp);                                       \
            xm[s] = *(const bf16x8*)(xp + XLVL);                                \
            xl[s] = *(const bf16x8*)(xp + 2 * XLVL); } } }

#define STEP(K, CH, CM, CL, NH, NM, NL) {                                       \
    __syncthreads();                                                            \
    _Pragma("unroll") for (int s = 0; s < 2; ++s) {                             \
        int r = rw2 + s * 64;                                                   \
        int key = r & 7;                                                        \
        char* rowA = (char*)PA + r * 128;                                       \
        char* rowL = (char*)PL + r * 128;                                       \
        *(bf16x8*)(rowA + ((ch ^ key) * 16))       = xh[s];                     \
        *(bf16x8*)(rowA + (((ch + 4) ^ key) * 16)) = xm[s];                     \
        *(bf16x8*)(rowL + ((ch ^ key) * 16))       = xl[s]; }                   \
    __syncthreads();                                                            \
    if ((K) + 1 < 64) { LOADX((K) + 1) LOADW((K) + 1, NH, NM, NL) }             \
    _Pragma("unroll") for (int mf = 0; mf < 4; ++mf) {                          \
        int row = wm * 64 + mf * 16 + lr16;                                     \
        int key = row & 7;                                                      \
        const char* rowA = (const char*)PA + row * 128;                         \
        const char* rowL = (const char*)PL + row * 128;                         \
        bf16x8 ah = *(const bf16x8*)(rowA + ((kb ^ key) * 16));                 \
        bf16x8 am = *(const bf16x8*)(rowA + (((kb + 4) ^ key) * 16));           \
        bf16x8 al = *(const bf16x8*)(rowL + ((kb ^ key) * 16));                 \
        _Pragma("unroll") for (int nf = 0; nf < 4; ++nf)                        \
            acc[mf][nf] = __builtin_amdgcn_mfma_f32_16x16x32_bf16(ah, CH[nf], acc[mf][nf], 0, 0, 0); \
        _Pragma("unroll") for (int nf = 0; nf < 4; ++nf)                        \
            acc[mf][nf] = __builtin_amdgcn_mfma_f32_16x16x32_bf16(ah, CM[nf], acc[mf][nf], 0, 0, 0); \
        _Pragma("unroll") for (int nf = 0; nf < 4; ++nf)                        \
            acc[mf][nf] = __builtin_amdgcn_mfma_f32_16x16x32_bf16(am, CH[nf], acc[mf][nf], 0, 0, 0); \
        _Pragma("unroll") for (int nf = 0; nf < 4; ++nf)                        \
            acc[mf][nf] = __builtin_amdgcn_mfma_f32_16x16x32_bf16(am, CM[nf], acc[mf][nf], 0, 0, 0); \
        _Pragma("unroll") for (int nf = 0; nf < 4; ++nf)                        \
            acc[mf][nf] = __builtin_amdgcn_mfma_f32_16x16x32_bf16(ah, CL[nf], acc[mf][nf], 0, 0, 0); \
        _Pragma("unroll") for (int nf = 0; nf < 4; ++nf)                        \
            acc[mf][nf] = __builtin_amdgcn_mfma_f32_16x16x32_bf16(al, CH[nf], acc[mf][nf], 0, 0, 0); \
    } }

    LOADX(0)
    LOADW(0, W0h, W0m, W0l)

#pragma unroll 1
    for (int kk = 0; kk < 64; kk += 2) {
        STEP(kk,     W0h, W0m, W0l, W1h, W1m, W1l)
        STEP(kk + 1, W1h, W1m, W1l, W0h, W0m, W0l)
    }
#undef LOADW
#undef LOADX
#undef STEP

#pragma unroll
    for (int mf = 0; mf < 4; ++mf)
#pragma unroll
        for (int nf = 0; nf < 4; ++nf) {
            int ic = i0 + wn * 64 + nf * 16 + lr16;
#pragma unroll
            for (int q = 0; q < 4; ++q) {
                int t = t0 + wm * 64 + mf * 16 + kb * 4 + q;
                y[((size_t)t * NB + b) * NI + ic] = acc[mf][nf][q];
            }
        }
}

// ---------------- MFMA conv (R10 fallback: fp32 x + in-kernel split3) ----------------
__global__ __launch_bounds__(256, 2) void conv_mfma(const float* __restrict__ x,
                                                    const short* __restrict__ WF,
                                                    float* __restrict__ y) {
    __shared__ __align__(16) short PA[128][64];
    __shared__ __align__(16) short PL[128][64];

    const int t0 = blockIdx.x * 128;
    const int i0 = blockIdx.y * 128;
    const int b  = blockIdx.z;
    const int tid = threadIdx.x;

    const int ch   = tid & 3;
    const int rw2  = tid >> 2;
    const int l    = tid & 63;
    const int wid  = tid >> 6;
    const int lr16 = l & 15;
    const int kb   = l >> 4;
    const int wm   = wid >> 1;
    const int wn   = wid & 1;

    const short* pnf[4];
#pragma unroll
    for (int nf = 0; nf < 4; ++nf) {
        int ig = (i0 + wn * 64 + nf * 16) >> 4;
        pnf[nf] = WF + (size_t)ig * 32768 + l * 8;
    }

    floatx4 acc[4][4];
#pragma unroll
    for (int mf = 0; mf < 4; ++mf)
#pragma unroll
        for (int nf = 0; nf < 4; ++nf)
#pragma unroll
            for (int e = 0; e < 4; ++e) acc[mf][nf][e] = 0.f;

    float4 ga[2][2];
    bf16x8 W0h[4], W0m[4], W0l[4], W1h[4], W1m[4], W1l[4];

#define LOADW(K, H, M, L_) {                                                    \
    int koff = ((((K) >> 2) * 16 + ((K) & 3) * 4)) * 128;                       \
    _Pragma("unroll") for (int nf = 0; nf < 4; ++nf) {                          \
        const short* p = pnf[nf] + koff;                                        \
        H[nf]  = *(const bf16x8*)(p);                                           \
        M[nf]  = *(const bf16x8*)(p + LVL);                                     \
        L_[nf] = *(const bf16x8*)(p + 2 * LVL); } }

#define STEP(K, CH, CM, CL, NH, NM, NL) {                                       \
    __syncthreads();                                                            \
    _Pragma("unroll") for (int s = 0; s < 2; ++s) {                             \
        int r = rw2 + s * 64;                                                   \
        int key = r & 7;                                                        \
        char* rowA = (char*)PA + r * 128;                                       \
        char* rowL = (char*)PL + r * 128;                                       \
        S3 a0 = split3(ga[s][0].x), a1 = split3(ga[s][0].y),                    \
           a2 = split3(ga[s][0].z), a3 = split3(ga[s][0].w),                    \
           a4 = split3(ga[s][1].x), a5 = split3(ga[s][1].y),                    \
           a6 = split3(ga[s][1].z), a7 = split3(ga[s][1].w);                    \
        bf16x8 h8, m8, l8;                                                      \
        h8[0]=a0.h; h8[1]=a1.h; h8[2]=a2.h; h8[3]=a3.h;                         \
        h8[4]=a4.h; h8[5]=a5.h; h8[6]=a6.h; h8[7]=a7.h;                         \
        m8[0]=a0.m; m8[1]=a1.m; m8[2]=a2.m; m8[3]=a3.m;                         \
        m8[4]=a4.m; m8[5]=a5.m; m8[6]=a6.m; m8[7]=a7.m;                         \
        l8[0]=a0.l; l8[1]=a1.l; l8[2]=a2.l; l8[3]=a3.l;                         \
        l8[4]=a4.l; l8[5]=a5.l; l8[6]=a6.l; l8[7]=a7.l;                         \
        *(bf16x8*)(rowA + ((ch ^ key) * 16))       = h8;                        \
        *(bf16x8*)(rowA + (((ch + 4) ^ key) * 16)) = m8;                        \
        *(bf16x8*)(rowL + ((ch ^ key) * 16))       = l8; }                      \
    __syncthreads();                                                            \
    if ((K) + 1 < 64) {                                                         \
        int kn = (K) + 1, dn = kn >> 2, j0n = (kn & 3) << 5;                    \
        _Pragma("unroll") for (int s = 0; s < 2; ++s) {                         \
            int r = rw2 + s * 64;                                               \
            int t = t0 + r - dn;                                                \
            float4 z4 = make_float4(0.f, 0.f, 0.f, 0.f);                        \
            ga[s][0] = z4; ga[s][1] = z4;                                       \
            if (t >= 0) {                                                       \
                const float* ax = x + ((size_t)t * NB + b) * NJ + j0n + ch * 8; \
                ga[s][0] = *(const float4*)ax;                                  \
                ga[s][1] = *(const float4*)(ax + 4); } }                        \
        LOADW(kn, NH, NM, NL) }                                                 \
    _Pragma("unroll") for (int mf = 0; mf < 4; ++mf) {                          \
        int row = wm * 64 + mf * 16 + lr16;                                     \
        int key = row & 7;                                                      \
        const char* rowA = (const char*)PA + row * 128;                         \
        const char* rowL = (const char*)PL + row * 128;                         \
        bf16x8 ah = *(const bf16x8*)(rowA + ((kb ^ key) * 16));                 \
        bf16x8 am = *(const bf16x8*)(rowA + (((kb + 4) ^ key) * 16));           \
        bf16x8 al = *(const bf16x8*)(rowL + ((kb ^ key) * 16));                 \
        _Pragma("unroll") for (int nf = 0; nf < 4; ++nf)                        \
            acc[mf][nf] = __builtin_amdgcn_mfma_f32_16x16x32_bf16(ah, CH[nf], acc[mf][nf], 0, 0, 0); \
        _Pragma("unroll") for (int nf = 0; nf < 4; ++nf)                        \
            acc[mf][nf] = __builtin_amdgcn_mfma_f32_16x16x32_bf16(ah, CM[nf], acc[mf][nf], 0, 0, 0); \
        _Pragma("unroll") for (int nf = 0; nf < 4; ++nf)                        \
            acc[mf][nf] = __builtin_amdgcn_mfma_f32_16x16x32_bf16(am, CH[nf], acc[mf][nf], 0, 0, 0); \
        _Pragma("unroll") for (int nf = 0; nf < 4; ++nf)                        \
            acc[mf][nf] = __builtin_amdgcn_mfma_f32_16x16x32_bf16(am, CM[nf], acc[mf][nf], 0, 0, 0); \
        _Pragma("unroll") for (int nf = 0; nf < 4; ++nf)                        \
            acc[mf][nf] = __builtin_amdgcn_mfma_f32_16x16x32_bf16(ah, CL[nf], acc[mf][nf], 0, 0, 0); \
        _Pragma("unroll") for (int nf = 0; nf < 4; ++nf)                        \
            acc[mf][nf] = __builtin_amdgcn_mfma_f32_16x16x32_bf16(al, CH[nf], acc[mf][nf], 0, 0, 0); \
    } }

#pragma unroll
    for (int s = 0; s < 2; ++s) {
        int r = rw2 + s * 64;
        int t = t0 + r;
        const float* ax = x + ((size_t)t * NB + b) * NJ + ch * 8;
        ga[s][0] = *(const float4*)ax;
        ga[s][1] = *(const float4*)(ax + 4);
    }
    LOADW(0, W0h, W0m, W0l)

#pragma unroll 1
    for (int kk = 0; kk < 64; kk += 2) {
        STEP(kk,     W0h, W0m, W0l, W1h, W1m, W1l)
        STEP(kk + 1, W1h, W1m, W1l, W0h, W0m, W0l)
    }
#undef LOADW
#undef STEP

#pragma unroll
    for (int mf = 0; mf < 4; ++mf)
#pragma unroll
        for (int nf = 0; nf < 4; ++nf) {
            int ic = i0 + wn * 64 + nf * 16 + lr16;
#pragma unroll
            for (int q = 0; q < 4; ++q) {
                int t = t0 + wm * 64 + mf * 16 + kb * 4 + q;
                y[((size_t)t * NB + b) * NI + ic] = acc[mf][nf][q];
            }
        }
}

// ---------------- BN stats pass 1 ----------------
__global__ __launch_bounds__(256) void red1(const float* __restrict__ y,
                                            float* __restrict__ part) {
    int r0 = blockIdx.x * 128;
    int c  = threadIdx.x;
    float s0 = 0.f, q0 = 0.f, s1 = 0.f, q1 = 0.f;
#pragma unroll 4
    for (int r = 0; r < 128; ++r) {
        float v0 = y[(size_t)(r0 + r) * NI + c];
        float v1 = y[(size_t)(r0 + r) * NI + c + 256];
        s0 += v0; q0 = fmaf(v0, v0, q0);
        s1 += v1; q1 = fmaf(v1, v1, q1);
    }
    part[blockIdx.x * NI + c]            = s0;
    part[blockIdx.x * NI + c + 256]      = s1;
    part[256 * NI + blockIdx.x * NI + c]       = q0;
    part[256 * NI + blockIdx.x * NI + c + 256] = q1;
}

// ---------------- BN stats pass 2 ----------------
__global__ __launch_bounds__(512) void red2(const float* __restrict__ part,
                                            const float* __restrict__ gamma,
                                            const float* __restrict__ bbeta,
                                            float* __restrict__ sb) {
    int c = threadIdx.x;
    double s = 0.0, q = 0.0;
#pragma unroll 8
    for (int p = 0; p < 256; ++p) {
        s += (double)part[p * NI + c];
        q += (double)part[256 * NI + p * NI + c];
    }
    double mean = s / 32768.0;
    double var  = q / 32768.0 - mean * mean;
    double scale = (double)gamma[c] / sqrt(var + 1e-5);
    sb[c]      = (float)scale;
    sb[NI + c] = (float)((double)bbeta[c] - mean * scale);
}

// ---------------- soft-reset LIF scan, in-place over y (=d_out) ----------------
__global__ __launch_bounds__(64) void scan_kern(float* __restrict__ y,
                                                const float* __restrict__ sb,
                                                const float* __restrict__ beta,
                                                const float* __restrict__ U0) {
    int g = blockIdx.x * 64 + threadIdx.x;
    int i = g & (NI - 1);
    float scale = sb[i];
    float bias  = sb[NI + i];
    float bet = beta[i];
    float omb = 1.f - bet;
    float u = U0[g];
    float s = 0.f;
    float* yp = y + g;

    float A[32], Bv[32];
#pragma unroll
    for (int r = 0; r < 32; ++r) A[r] = yp[(size_t)r * 16384];

    for (int t0 = 0; t0 < TT; t0 += 64) {
#pragma unroll
        for (int r = 0; r < 32; ++r) Bv[r] = yp[(size_t)(t0 + 32 + r) * 16384];
#pragma unroll
        for (int r = 0; r < 32; ++r) {
            float z = fmaf(A[r], scale, bias);
            u = fmaf(bet, u - s, omb * z);
            s = (u >= 1.f) ? 1.f : 0.f;
            yp[(size_t)(t0 + r) * 16384] = s;
        }
        if (t0 + 64 < TT) {
#pragma unroll
            for (int r = 0; r < 32; ++r) A[r] = yp[(size_t)(t0 + 64 + r) * 16384];
        }
#pragma unroll
        for (int r = 0; r < 32; ++r) {
            float z = fmaf(Bv[r], scale, bias);
            u = fmaf(bet, u - s, omb * z);
            s = (u >= 1.f) ? 1.f : 0.f;
            yp[(size_t)(t0 + 32 + r) * 16384] = s;
        }
    }
}

extern "C" void kernel_launch(void* const* d_in, const int* in_sizes, int n_in,
                              void* d_out, int out_size, void* d_ws, size_t ws_size,
                              hipStream_t stream) {
    const float* x       = (const float*)d_in[0];
    const float* delay_w = (const float*)d_in[1];
    const float* delay_P = (const float*)d_in[2];
    const float* beta    = (const float*)d_in[3];
    const float* bn_g    = (const float*)d_in[4];
    const float* bn_b    = (const float*)d_in[5];
    const float* U0      = (const float*)d_in[6];
    float* y = (float*)d_out;

    // ws layout: WF [0, 6 MiB) [R10-proven]; XF [6 MiB, 30 MiB) if it fits.
    // part/sb ALIAS WF (kernels stream-serialize; every buffer fully rewritten
    // before each read -> deterministic under graph replay).
    short* WF   = (short*)d_ws;
    short* XF   = WF + 3 * (size_t)LVL;
    float* part = (float*)d_ws;
    float* sb   = (float*)d_ws + 2 * 256 * NI;

    const bool use_xf = ws_size >= (size_t)(3 * LVL + 3 * XLVL) * sizeof(short);

    dcls_kern<<<dim3(NI * NJ / 256), dim3(256), 0, stream>>>(delay_w, delay_P, WF);
    if (use_xf) {
        xsplit_kern<<<dim3(TT * NB * NJ / (256 * 8)), dim3(256), 0, stream>>>(x, XF);
        conv_mfma_xf<<<dim3(TT / 128, NI / 128, NB), dim3(256), 0, stream>>>(XF, WF, y);
    } else {
        conv_mfma<<<dim3(TT / 128, NI / 128, NB), dim3(256), 0, stream>>>(x, WF, y);
    }
    red1<<<dim3(TT * NB / 128), dim3(256), 0, stream>>>(y, part);
    red2<<<dim3(1), dim3(512), 0, stream>>>(part, bn_g, bn_b, sb);
    scan_kern<<<dim3(NB * NI / 64), dim3(64), 0, stream>>>(y, sb, beta, U0);
}

// Round 13
// 368.642 us; speedup vs baseline: 2.9008x; 2.9008x over previous
//
#include <hip/hip_runtime.h>

#define TT 1024
#define NB 32
#define NJ 128
#define NI 512
#define KD 16
#define LVL 1048576   // shorts per level in WF (512*2048)

typedef short bf16x8 __attribute__((ext_vector_type(8)));
typedef float floatx4 __attribute__((ext_vector_type(4)));

struct S3 { short h, m, l; };

// 3-way bf16 truncation split: v = h + m + l + O(2^-24 v). Residuals exact.
__device__ __forceinline__ S3 split3(float v) {
    S3 o;
    unsigned hb = __float_as_uint(v) & 0xFFFF0000u;
    float hf = __uint_as_float(hb);
    float r1 = v - hf;
    unsigned mb = __float_as_uint(r1) & 0xFFFF0000u;
    float mf = __uint_as_float(mb);
    float r2 = r1 - mf;
    unsigned lb = __float_as_uint(r2) & 0xFFFF0000u;
    o.h = (short)(hb >> 16);
    o.m = (short)(mb >> 16);
    o.l = (short)(lb >> 16);
    return o;
}

// ---------------- DCLS: W in 3-level bf16 MFMA B-frag layout [R10-proven] ----------------
// k = d*128 + j. WF[lvl][ig=i>>4][ko=k>>3][c16=i&15][kq=k&7]: a wave's B-frag
// load (4 k-octets x 16 cols) is one contiguous 1KB block = 1 dwordx4/lane.
__global__ __launch_bounds__(256) void dcls_kern(const float* __restrict__ w,
                                                 const float* __restrict__ P,
                                                 short* __restrict__ WF) {
    int idx = blockIdx.x * 256 + threadIdx.x;   // idx = i*128 + j
    int j = idx & (NJ - 1);
    int i = idx >> 7;
    float wv = w[i * NJ + j];
    float c  = P[i * NJ + j] + (float)(KD / 2);
    float g[KD];
    float s = 0.f;
#pragma unroll
    for (int k = 0; k < KD; ++k) {
        float u = (float)k - c;
        g[k] = expf(-2.0f * u * u);
        s += g[k];
    }
    float inv = wv / (s + 1e-7f);
    size_t base = (size_t)(i >> 4) * 32768 + (size_t)(j >> 3) * 128 + (i & 15) * 8 + (j & 7);
#pragma unroll
    for (int d = 0; d < KD; ++d) {
        S3 sp = split3(g[(KD - 1) - d] * inv);   // conv flip
        size_t off = base + (size_t)d * 2048;
        WF[off]           = sp.h;
        WF[off + LVL]     = sp.m;
        WF[off + 2 * LVL] = sp.l;
    }
}

// ---------------- MFMA conv: y[t,b,i] = sum_{d,j} W[i][d*128+j] * x[t-d,b,j] ----
// R10 structure + DOUBLE-BUFFERED LDS: per step {stage k+1 -> buf^1 || issue x loads
// k+2 || W-frag loads k+1 || MFMA k from buf} then ONE barrier. Stage VALU/ds_write
// overlap the MFMA cluster (independent pipes); barriers halve vs R10.
// 6 MFMA products: AhWh + AhWm + AmWh + AmWm + AhWl + AlWh.
__global__ __launch_bounds__(256, 2) void conv_mfma(const float* __restrict__ x,
                                                    const short* __restrict__ WF,
                                                    float* __restrict__ y) {
    __shared__ __align__(16) short PA[2][128][64];   // [Ah | Am] per buffer (16 KB each)
    __shared__ __align__(16) short PL[2][128][64];   // [Al | --] per buffer

    const int t0 = blockIdx.x * 128;
    const int i0 = blockIdx.y * 128;
    const int b  = blockIdx.z;
    const int tid = threadIdx.x;

    const int ch   = tid & 3;            // staging: 4 chunks x 8 floats = 32 cols
    const int rw2  = tid >> 2;           // 0..63
    const int l    = tid & 63;
    const int wid  = tid >> 6;           // wave 0..3
    const int lr16 = l & 15;
    const int kb   = l >> 4;             // k-octet 0..3
    const int wm   = wid >> 1;           // 0..1 -> 64 t-rows
    const int wn   = wid & 1;            // 0..1 -> 64 i-cols

    const short* pnf[4];
#pragma unroll
    for (int nf = 0; nf < 4; ++nf) {
        int ig = (i0 + wn * 64 + nf * 16) >> 4;
        pnf[nf] = WF + (size_t)ig * 32768 + l * 8;
    }

    floatx4 acc[4][4];
#pragma unroll
    for (int mf = 0; mf < 4; ++mf)
#pragma unroll
        for (int nf = 0; nf < 4; ++nf)
#pragma unroll
            for (int e = 0; e < 4; ++e) acc[mf][nf][e] = 0.f;

    float4 ga[2][2];
    bf16x8 W0h[4], W0m[4], W0l[4], W1h[4], W1m[4], W1l[4];

#define LOADW(K, H, M, L_) {                                                    \
    int koff = ((((K) >> 2) * 16 + ((K) & 3) * 4)) * 128;                       \
    _Pragma("unroll") for (int nf = 0; nf < 4; ++nf) {                          \
        const short* p = pnf[nf] + koff;                                        \
        H[nf]  = *(const bf16x8*)(p);                                           \
        M[nf]  = *(const bf16x8*)(p + LVL);                                     \
        L_[nf] = *(const bf16x8*)(p + 2 * LVL); } }

#define LOADX(K) {                                                              \
    int dn = (K) >> 2, j0n = ((K) & 3) << 5;                                    \
    _Pragma("unroll") for (int s = 0; s < 2; ++s) {                             \
        int r = rw2 + s * 64;                                                   \
        int t = t0 + r - dn;                                                    \
        float4 z4 = make_float4(0.f, 0.f, 0.f, 0.f);                            \
        ga[s][0] = z4; ga[s][1] = z4;                                           \
        if (t >= 0) {                                                           \
            const float* ax = x + ((size_t)t * NB + b) * NJ + j0n + ch * 8;     \
            ga[s][0] = *(const float4*)ax;                                      \
            ga[s][1] = *(const float4*)(ax + 4); } } }

#define STAGEW(BUFA, BUFL) {                                                    \
    _Pragma("unroll") for (int s = 0; s < 2; ++s) {                             \
        int r = rw2 + s * 64;                                                   \
        int key = r & 7;                                                        \
        char* rowA = (char*)(BUFA) + r * 128;                                   \
        char* rowL = (char*)(BUFL) + r * 128;                                   \
        S3 a0 = split3(ga[s][0].x), a1 = split3(ga[s][0].y),                    \
           a2 = split3(ga[s][0].z), a3 = split3(ga[s][0].w),                    \
           a4 = split3(ga[s][1].x), a5 = split3(ga[s][1].y),                    \
           a6 = split3(ga[s][1].z), a7 = split3(ga[s][1].w);                    \
        bf16x8 h8, m8, l8;                                                      \
        h8[0]=a0.h; h8[1]=a1.h; h8[2]=a2.h; h8[3]=a3.h;                         \
        h8[4]=a4.h; h8[5]=a5.h; h8[6]=a6.h; h8[7]=a7.h;                         \
        m8[0]=a0.m; m8[1]=a1.m; m8[2]=a2.m; m8[3]=a3.m;                         \
        m8[4]=a4.m; m8[5]=a5.m; m8[6]=a6.m; m8[7]=a7.m;                         \
        l8[0]=a0.l; l8[1]=a1.l; l8[2]=a2.l; l8[3]=a3.l;                         \
        l8[4]=a4.l; l8[5]=a5.l; l8[6]=a6.l; l8[7]=a7.l;                         \
        *(bf16x8*)(rowA + ((ch ^ key) * 16))       = h8;                        \
        *(bf16x8*)(rowA + (((ch + 4) ^ key) * 16)) = m8;                        \
        *(bf16x8*)(rowL + ((ch ^ key) * 16))       = l8; } }

#define DOMFMA(BUFA, BUFL, CH, CM, CL) {                                        \
    _Pragma("unroll") for (int mf = 0; mf < 4; ++mf) {                          \
        int row = wm * 64 + mf * 16 + lr16;                                     \
        int key = row & 7;                                                      \
        const char* rowA = (const char*)(BUFA) + row * 128;                     \
        const char* rowL = (const char*)(BUFL) + row * 128;                     \
        bf16x8 ah = *(const bf16x8*)(rowA + ((kb ^ key) * 16));                 \
        bf16x8 am = *(const bf16x8*)(rowA + (((kb + 4) ^ key) * 16));           \
        bf16x8 al = *(const bf16x8*)(rowL + ((kb ^ key) * 16));                 \
        _Pragma("unroll") for (int nf = 0; nf < 4; ++nf)                        \
            acc[mf][nf] = __builtin_amdgcn_mfma_f32_16x16x32_bf16(ah, CH[nf], acc[mf][nf], 0, 0, 0); \
        _Pragma("unroll") for (int nf = 0; nf < 4; ++nf)                        \
            acc[mf][nf] = __builtin_amdgcn_mfma_f32_16x16x32_bf16(ah, CM[nf], acc[mf][nf], 0, 0, 0); \
        _Pragma("unroll") for (int nf = 0; nf < 4; ++nf)                        \
            acc[mf][nf] = __builtin_amdgcn_mfma_f32_16x16x32_bf16(am, CH[nf], acc[mf][nf], 0, 0, 0); \
        _Pragma("unroll") for (int nf = 0; nf < 4; ++nf)                        \
            acc[mf][nf] = __builtin_amdgcn_mfma_f32_16x16x32_bf16(am, CM[nf], acc[mf][nf], 0, 0, 0); \
        _Pragma("unroll") for (int nf = 0; nf < 4; ++nf)                        \
            acc[mf][nf] = __builtin_amdgcn_mfma_f32_16x16x32_bf16(ah, CL[nf], acc[mf][nf], 0, 0, 0); \
        _Pragma("unroll") for (int nf = 0; nf < 4; ++nf)                        \
            acc[mf][nf] = __builtin_amdgcn_mfma_f32_16x16x32_bf16(al, CH[nf], acc[mf][nf], 0, 0, 0); \
    } }

    // prologue: stage tile 0 into buf0; preload x(1) and W(0)
    LOADX(0)
    STAGEW(PA[0], PL[0])
    LOADX(1)
    LOADW(0, W0h, W0m, W0l)
    __syncthreads();

#pragma unroll 1
    for (int kk = 0; kk < 64; kk += 2) {
        // --- step kk: consume buf0; stage kk+1 -> buf1 (overlaps MFMA) ---
        if (kk + 1 < 64) { STAGEW(PA[1], PL[1]) }       // ga holds tile kk+1
        if (kk + 2 < 64) { LOADX(kk + 2) }              // ga <- tile kk+2 (async)
        if (kk + 1 < 64) { LOADW(kk + 1, W1h, W1m, W1l) }
        DOMFMA(PA[0], PL[0], W0h, W0m, W0l)
        __syncthreads();
        // --- step kk+1: consume buf1; stage kk+2 -> buf0 ---
        if (kk + 2 < 64) { STAGEW(PA[0], PL[0]) }       // ga holds tile kk+2
        if (kk + 3 < 64) { LOADX(kk + 3) }
        if (kk + 2 < 64) { LOADW(kk + 2, W0h, W0m, W0l) }
        if (kk + 1 < 64) { DOMFMA(PA[1], PL[1], W1h, W1m, W1l) }
        __syncthreads();
    }
#undef LOADW
#undef LOADX
#undef STAGEW
#undef DOMFMA

    // ---- epilogue: C/D layout col=lane&15, row=(lane>>4)*4+reg [m89-verified] ----
#pragma unroll
    for (int mf = 0; mf < 4; ++mf)
#pragma unroll
        for (int nf = 0; nf < 4; ++nf) {
            int ic = i0 + wn * 64 + nf * 16 + lr16;
#pragma unroll
            for (int q = 0; q < 4; ++q) {
                int t = t0 + wm * 64 + mf * 16 + kb * 4 + q;
                y[((size_t)t * NB + b) * NI + ic] = acc[mf][nf][q];
            }
        }
}

// ---------------- BN stats pass 1: per-block partial sum/sumsq over 128 rows ----
__global__ __launch_bounds__(256) void red1(const float* __restrict__ y,
                                            float* __restrict__ part) {
    int r0 = blockIdx.x * 128;
    int c  = threadIdx.x;
    float s0 = 0.f, q0 = 0.f, s1 = 0.f, q1 = 0.f;
#pragma unroll 4
    for (int r = 0; r < 128; ++r) {
        float v0 = y[(size_t)(r0 + r) * NI + c];
        float v1 = y[(size_t)(r0 + r) * NI + c + 256];
        s0 += v0; q0 = fmaf(v0, v0, q0);
        s1 += v1; q1 = fmaf(v1, v1, q1);
    }
    part[blockIdx.x * NI + c]            = s0;
    part[blockIdx.x * NI + c + 256]      = s1;
    part[256 * NI + blockIdx.x * NI + c]       = q0;
    part[256 * NI + blockIdx.x * NI + c + 256] = q1;
}

// ---------------- BN stats pass 2: combine partials (double), emit scale/bias ----
__global__ __launch_bounds__(512) void red2(const float* __restrict__ part,
                                            const float* __restrict__ gamma,
                                            const float* __restrict__ bbeta,
                                            float* __restrict__ sb) {
    int c = threadIdx.x;
    double s = 0.0, q = 0.0;
#pragma unroll 8
    for (int p = 0; p < 256; ++p) {
        s += (double)part[p * NI + c];
        q += (double)part[256 * NI + p * NI + c];
    }
    double mean = s / 32768.0;
    double var  = q / 32768.0 - mean * mean;
    double scale = (double)gamma[c] / sqrt(var + 1e-5);
    sb[c]      = (float)scale;
    sb[NI + c] = (float)((double)bbeta[c] - mean * scale);
}

// ---------------- soft-reset LIF scan, in-place over y (=d_out) ----------------
__global__ __launch_bounds__(64) void scan_kern(float* __restrict__ y,
                                                const float* __restrict__ sb,
                                                const float* __restrict__ beta,
                                                const float* __restrict__ U0) {
    int g = blockIdx.x * 64 + threadIdx.x;   // 0..16383 = b*512 + i
    int i = g & (NI - 1);
    float scale = sb[i];
    float bias  = sb[NI + i];
    float bet = beta[i];
    float omb = 1.f - bet;
    float u = U0[g];
    float s = 0.f;
    float* yp = y + g;

    float A[32], Bv[32];
#pragma unroll
    for (int r = 0; r < 32; ++r) A[r] = yp[(size_t)r * 16384];

    for (int t0 = 0; t0 < TT; t0 += 64) {
#pragma unroll
        for (int r = 0; r < 32; ++r) Bv[r] = yp[(size_t)(t0 + 32 + r) * 16384];
#pragma unroll
        for (int r = 0; r < 32; ++r) {
            float z = fmaf(A[r], scale, bias);
            u = fmaf(bet, u - s, omb * z);
            s = (u >= 1.f) ? 1.f : 0.f;
            yp[(size_t)(t0 + r) * 16384] = s;
        }
        if (t0 + 64 < TT) {
#pragma unroll
            for (int r = 0; r < 32; ++r) A[r] = yp[(size_t)(t0 + 64 + r) * 16384];
        }
#pragma unroll
        for (int r = 0; r < 32; ++r) {
            float z = fmaf(Bv[r], scale, bias);
            u = fmaf(bet, u - s, omb * z);
            s = (u >= 1.f) ? 1.f : 0.f;
            yp[(size_t)(t0 + 32 + r) * 16384] = s;
        }
    }
}

extern "C" void kernel_launch(void* const* d_in, const int* in_sizes, int n_in,
                              void* d_out, int out_size, void* d_ws, size_t ws_size,
                              hipStream_t stream) {
    const float* x       = (const float*)d_in[0];
    const float* delay_w = (const float*)d_in[1];
    const float* delay_P = (const float*)d_in[2];
    const float* beta    = (const float*)d_in[3];
    const float* bn_g    = (const float*)d_in[4];
    const float* bn_b    = (const float*)d_in[5];
    const float* U0      = (const float*)d_in[6];
    float* y = (float*)d_out;

    // ws layout (6 MiB total, R10-proven): WF occupies [0, 6 MiB). part/sb ALIAS
    // WF's space — safe because kernels serialize on the stream: dcls writes WF,
    // conv reads WF, THEN red1 clobbers [0,1 MiB) with partials, red2 writes sb.
    // Every buffer fully rewritten before each read -> deterministic under replay.
    short* WF   = (short*)d_ws;
    float* part = (float*)d_ws;
    float* sb   = (float*)d_ws + 2 * 256 * NI;

    dcls_kern<<<dim3(NI * NJ / 256), dim3(256), 0, stream>>>(delay_w, delay_P, WF);
    conv_mfma<<<dim3(TT / 128, NI / 128, NB), dim3(256), 0, stream>>>(x, WF, y);
    red1<<<dim3(TT * NB / 128), dim3(256), 0, stream>>>(y, part);
    red2<<<dim3(1), dim3(512), 0, stream>>>(part, bn_g, bn_b, sb);
    scan_kern<<<dim3(NB * NI / 64), dim3(64), 0, stream>>>(y, sb, beta, U0);
}